// Round 18
// baseline (56.257 us; speedup 1.0000x reference)
//
#include <hip/hip_runtime.h>
#include <hip/hip_bf16.h>

typedef __bf16 bf16x8 __attribute__((ext_vector_type(8)));
typedef float f32x4 __attribute__((ext_vector_type(4)));
typedef float f32x16 __attribute__((ext_vector_type(16)));
typedef unsigned int u32x2 __attribute__((ext_vector_type(2)));
typedef unsigned int u32x4 __attribute__((ext_vector_type(4)));
typedef unsigned short us8 __attribute__((ext_vector_type(8)));

#define MFMA32(a, b, c) __builtin_amdgcn_mfma_f32_32x32x16_bf16((a), (b), (c), 0, 0, 0)

// ---- constants ----
#define BATCH 8
#define SEQ 512
#define HID 768
#define NHEAD 12
#define HDIM 64

__device__ __forceinline__ unsigned short f2bf(float f) {
    unsigned int u = __float_as_uint(f);
    u += 0x7fffu + ((u >> 16) & 1u);
    return (unsigned short)(u >> 16);
}

__device__ __forceinline__ unsigned int cvtpk_bf16(float lo, float hi) {
    unsigned int r;
    asm("v_cvt_pk_bf16_f32 %0, %1, %2" : "=v"(r) : "v"(lo), "v"(hi));
    return r;
}

// ---- cvt v2 (unchanged): fp32 -> bf16 fragment-tiled, LDS-transposed ----
__global__ __launch_bounds__(256) void cvt_all_kernel(const float4* __restrict__ hs,
                                                      const float4* __restrict__ Wq,
                                                      const float4* __restrict__ Wk,
                                                      const float4* __restrict__ Wv,
                                                      unsigned short* __restrict__ hsb,
                                                      unsigned short* __restrict__ wb) {
    __shared__ us8 lds[768];   // 12 KB; index = cell ^ (row&7)

    const int tid = threadIdx.x;
    const int id = blockIdx.x;       // 0..799
    const int T = id >> 2;           // tile 0..199
    const int q = id & 3;            // kt-quarter 0..3

    const float4* src;
    int row0;
    unsigned short* dst;
    int Tout;
    if (T < 128) {
        src = hs; row0 = T * 32; dst = hsb; Tout = T;
    } else {
        int tw = T - 128;
        int which = tw / 24;
        src = (which == 0) ? Wq : ((which == 1) ? Wk : Wv);
        row0 = (tw - which * 24) * 32;
        dst = wb; Tout = tw;
    }

#pragma unroll
    for (int it = 0; it < 3; ++it) {
        int g = it * 256 + tid;
        int row = g / 24, ccl = g - row * 24;
        int fidx = (row0 + row) * 192 + (q * 24 + ccl) * 2;
        float4 v0 = src[fidx], v1 = src[fidx + 1];
        us8 o;
        o[0] = f2bf(v0.x); o[1] = f2bf(v0.y); o[2] = f2bf(v0.z); o[3] = f2bf(v0.w);
        o[4] = f2bf(v1.x); o[5] = f2bf(v1.y); o[6] = f2bf(v1.z); o[7] = f2bf(v1.w);
        int cell = row * 24 + ccl;
        lds[cell ^ (row & 7)] = o;
    }
    __syncthreads();

    const int w = tid >> 6, l = tid & 63;
    const int row = l & 31, h5 = l >> 5;
#pragma unroll
    for (int j = 0; j < 3; ++j) {
        int ktl = w * 3 + j;
        int kt = q * 12 + ktl;
        int cell = row * 24 + ktl * 2 + h5;
        us8 o = lds[cell ^ (row & 7)];
        *reinterpret_cast<us8*>(dst + ((size_t)Tout * 48 + kt) * 512 + l * 8) = o;
    }
}

// ---- fused QKV GEMM v10b: v10 + __launch_bounds__(512,6) -> VGPR<=85, 3 blocks/CU ----
__global__ __launch_bounds__(512, 6) void qkv_gemm_kernel(const unsigned short* __restrict__ hsb,
                                                          const unsigned short* __restrict__ wb,
                                                          const float* __restrict__ bq,
                                                          const float* __restrict__ bk,
                                                          const float* __restrict__ bv,
                                                          unsigned short* __restrict__ Qf,
                                                          unsigned short* __restrict__ Kf,
                                                          unsigned short* __restrict__ VTf) {
    __shared__ __align__(16) char smem[49152];
    float* combine = (float*)smem;                  // [4 quads][48 vals][64 lanes]
    unsigned short* tb = (unsigned short*)smem;     // transpose buf (<= 24KB used)

    const int tid = threadIdx.x;
    const int w = tid >> 6;               // 0..7
    const int l = tid & 63;
    const int lq = l & 31, h5 = l >> 5;
    const int quad = w & 3;
    const int kh = w >> 2;                // K-half: 0 -> kt 0..23, 1 -> kt 24..47
    const int qm = quad >> 1, qn = quad & 1;

    // XCD remap: 768 tiles = 64 tm x 12 tn; xcd owns 16tm x 6tn (A 1.5MB + B 1.7MB < 4MB L2)
    const int id = blockIdx.x;            // 0..767
    const int xcd = id & 7, j = id >> 3;  // j in [0,96) = 16 x 6
    const int tm = (xcd >> 1) * 16 + j / 6;   // 0..63  (64 M-rows each)
    const int tn = (xcd & 1) * 6 + j % 6;     // 0..11  (192 N-cols each)

    const int fa = tm * 2 + qm;           // A frag-row (32-row unit)
    const int fb0 = tn * 6 + qn * 3;      // B frag-cols fb0..fb0+2

    const unsigned short* pa  = hsb + (size_t)fa * 48 * 512 + kh * 24 * 512 + l * 8;
    const unsigned short* pb0 = wb + (size_t)fb0 * 48 * 512 + kh * 24 * 512 + l * 8;
    const unsigned short* pb1 = pb0 + 48 * 512;
    const unsigned short* pb2 = pb1 + 48 * 512;

    f32x16 acc0 = {}, acc1 = {}, acc2 = {};

#pragma unroll 4
    for (int kt = 0; kt < 24; ++kt) {
        bf16x8 a  = *reinterpret_cast<const bf16x8*>(pa + kt * 512);
        bf16x8 b0 = *reinterpret_cast<const bf16x8*>(pb0 + kt * 512);
        bf16x8 b1 = *reinterpret_cast<const bf16x8*>(pb1 + kt * 512);
        bf16x8 b2 = *reinterpret_cast<const bf16x8*>(pb2 + kt * 512);
        acc0 = MFMA32(a, b0, acc0);
        acc1 = MFMA32(a, b1, acc1);
        acc2 = MFMA32(a, b2, acc2);
    }

    f32x16 accs[3] = {acc0, acc1, acc2};

    // ---- split-K combine: kh=1 stores value-major (lane-contiguous, conflict-free) ----
    if (kh == 1) {
#pragma unroll
        for (int ni = 0; ni < 3; ++ni)
#pragma unroll
            for (int r = 0; r < 16; ++r)
                combine[(size_t)quad * 3072 + (ni * 16 + r) * 64 + l] = accs[ni][r];
    }
    __syncthreads();
    if (kh == 0) {
#pragma unroll
        for (int ni = 0; ni < 3; ++ni)
#pragma unroll
            for (int r = 0; r < 16; ++r)
                accs[ni][r] += combine[(size_t)quad * 3072 + (ni * 16 + r) * 64 + l];
    }
    __syncthreads();   // combine reads done; smem reusable as transpose buffer

    const int which = tn / 4;             // 0=Q (tn 0-3), 1=K (4-7), 2=V (8-11)
    const int b = tm >> 3;                // batch (8 tm-tiles of 64 rows = 512)

    // ---- phase A (kh==0): bias+scale, bf16, write swizzled LDS ----
    if (kh == 0) {
#pragma unroll
        for (int ni = 0; ni < 3; ++ni) {
            int d_local = qn * 96 + ni * 32 + lq;        // 0..191
            int col = tn * 192 + d_local;
            int oo = col - which * HID;
            const float* bias = (which == 0) ? bq : ((which == 1) ? bk : bv);
            float bvv = bias[oo];
            float scale = (which == 0) ? 0.125f : 1.0f;
#pragma unroll
            for (int g = 0; g < 4; ++g) {
                int s_base = qm * 32 + 8 * g + 4 * h5;   // 4-aligned, 0..60
                if (which == 2) {
                    ushort4 pk;
                    pk.x = f2bf(accs[ni][4 * g + 0] + bvv);
                    pk.y = f2bf(accs[ni][4 * g + 1] + bvv);
                    pk.z = f2bf(accs[ni][4 * g + 2] + bvv);
                    pk.w = f2bf(accs[ni][4 * g + 3] + bvv);
                    int byte = d_local * 128 + ((s_base * 2) ^ ((d_local & 7) << 4));
                    *reinterpret_cast<ushort4*>((char*)tb + byte) = pk;
                } else {
#pragma unroll
                    for (int r2 = 0; r2 < 4; ++r2) {
                        int s_local = s_base + r2;
                        int dbyte = d_local * 2;
                        int byte = s_local * 384 + (dbyte & 0x180)
                                 + ((dbyte ^ ((s_local & 7) << 4)) & 0x7F);
                        *reinterpret_cast<unsigned short*>((char*)tb + byte) =
                            f2bf((accs[ni][4 * g + r2] + bvv) * scale);
                    }
                }
            }
        }
    }
    __syncthreads();

    // ---- phase B (all 8 waves, 3 frags each = 24 frags/tile): coalesced writes ----
    if (which != 2) {
        unsigned short* dstF = (which == 0) ? Qf : Kf;
        const int tnb = tn - which * 4;
#pragma unroll
        for (int j2 = 0; j2 < 3; ++j2) {
            int fi = w * 3 + j2;                  // 0..23 = (qt_l*3 + hl)*4 + dc
            int dc = fi & 3;
            int t2 = fi >> 2;                     // 0..5
            int hl = t2 % 3, qt_l = t2 / 3;
            int head = tnb * 3 + hl;
            int qt = (tm & 7) * 2 + qt_l;
            int s_local = qt_l * 32 + lq;
            int dbyte = (hl * 64 + dc * 16 + h5 * 8) * 2;
            int byte = s_local * 384 + (dbyte & 0x180)
                     + ((dbyte ^ ((s_local & 7) << 4)) & 0x7F);
            us8 v = *reinterpret_cast<const us8*>((char*)tb + byte);
            size_t off = ((((size_t)(b * NHEAD + head)) * 16 + qt) * 4 + dc) * 512 + l * 8;
            *reinterpret_cast<us8*>(dstF + off) = v;
        }
    } else {
#pragma unroll
        for (int j2 = 0; j2 < 3; ++j2) {
            int fi = w * 3 + j2;                  // 0..23 = (nt*3 + hl)*4 + kt2l
            int kt2l = fi & 3;
            int t2 = fi >> 2;
            int hl = t2 % 3, nt = t2 / 3;
            int head = (tn - 8) * 3 + hl;
            int d_local = hl * 64 + nt * 32 + lq;
            int sbyte = kt2l * 32 + h5 * 16;
            int byte = d_local * 128 + (sbyte ^ ((d_local & 7) << 4));
            us8 v = *reinterpret_cast<const us8*>((char*)tb + byte);
            int kt2 = (tm & 7) * 4 + kt2l;
            size_t off = ((((size_t)(b * NHEAD + head)) * 2 + nt) * 32 + kt2) * 512 + l * 8;
            *reinterpret_cast<us8*>(VTf + off) = v;
        }
    }
}

// ---- attention v7 (unchanged): fully-unrolled kb loop, fragment-tiled loads ----
__global__ __launch_bounds__(256, 3) void attn_kernel(const unsigned short* __restrict__ Qf,
                                                      const unsigned short* __restrict__ Kf,
                                                      const unsigned short* __restrict__ VTf,
                                                      const float* __restrict__ mask,
                                                      float* __restrict__ out) {
    __shared__ float lds_ctx[2][32][64];   // 16 KB
    __shared__ float lds_den[2][32];       // 256 B

    const int tid = threadIdx.x;
    const int w = tid >> 6;
    const int l = tid & 63;
    const int lq = l & 31;
    const int h5 = l >> 5;
    const int qg = w & 1;
    const int kh = w >> 1;

    const int id = blockIdx.x;   // 0..767
    const int hh = id % 96;
    const int qb = id / 96;
    const int b = hh / 12;
    const int hd = hh % 12;

    const int bh = b * NHEAD + hd;
    const int q0 = qb * 64 + qg * 32;
    const float4* mask4 = (const float4*)mask;

    bf16x8 qf[4];
    {
        const unsigned short* qbase = Qf + (((size_t)bh * 16 + (qb * 2 + qg)) * 4) * 512 + l * 8;
#pragma unroll
        for (int dc = 0; dc < 4; ++dc)
            qf[dc] = *reinterpret_cast<const bf16x8*>(qbase + dc * 512);
    }

    const unsigned short* kbase  = Kf + (((size_t)bh * 16 + kh * 8) * 4) * 512 + l * 8;
    const unsigned short* vbase0 = VTf + (((size_t)bh * 2 + 0) * 32 + kh * 16) * 512 + l * 8;
    const unsigned short* vbase1 = VTf + (((size_t)bh * 2 + 1) * 32 + kh * 16) * 512 + l * 8;

    f32x16 ctx0 = {};
    f32x16 ctx1 = {};
    float den = 0.f;

#pragma unroll
    for (int kb = 0; kb < 8; ++kb) {
        bf16x8 kf[4];
#pragma unroll
        for (int dc = 0; dc < 4; ++dc)
            kf[dc] = *reinterpret_cast<const bf16x8*>(kbase + (kb * 4 + dc) * 512);

        f32x16 T = {};
#pragma unroll
        for (int dc = 0; dc < 4; ++dc)
            T = MFMA32(kf[dc], qf[dc], T);

        bf16x8 vf00 = *reinterpret_cast<const bf16x8*>(vbase0 + kb * 2 * 512);
        bf16x8 vf10 = *reinterpret_cast<const bf16x8*>(vbase0 + (kb * 2 + 1) * 512);
        bf16x8 vf01 = *reinterpret_cast<const bf16x8*>(vbase1 + kb * 2 * 512);
        bf16x8 vf11 = *reinterpret_cast<const bf16x8*>(vbase1 + (kb * 2 + 1) * 512);

        const int k0 = kh * 256 + kb * 32;
        float4 mv[4];
#pragma unroll
        for (int g = 0; g < 4; ++g)
            mv[g] = mask4[b * 128 + (k0 >> 2) + 2 * g + h5];

        float p[16];
#pragma unroll
        for (int r = 0; r < 16; ++r) {
            float mval = (r & 3) == 0 ? mv[r >> 2].x : ((r & 3) == 1 ? mv[r >> 2].y
                       : ((r & 3) == 2 ? mv[r >> 2].z : mv[r >> 2].w));
            p[r] = __expf(T[r] + mval);
            den += p[r];
        }

        bf16x8 pa[2];
#pragma unroll
        for (int c = 0; c < 2; ++c) {
            int base = c * 8;
            unsigned int lo01 = cvtpk_bf16(p[base + 0], p[base + 1]);
            unsigned int lo23 = cvtpk_bf16(p[base + 2], p[base + 3]);
            unsigned int hi01 = cvtpk_bf16(p[base + 4], p[base + 5]);
            unsigned int hi23 = cvtpk_bf16(p[base + 6], p[base + 7]);
            u32x2 s1 = __builtin_amdgcn_permlane32_swap(lo01, hi01, false, false);  // {w0, w2}
            u32x2 s2 = __builtin_amdgcn_permlane32_swap(lo23, hi23, false, false);  // {w1, w3}
            u32x4 words = {s1[0], s2[0], s1[1], s2[1]};
            pa[c] = __builtin_bit_cast(bf16x8, words);
        }

        ctx0 = MFMA32(pa[0], vf00, ctx0);
        ctx0 = MFMA32(pa[1], vf10, ctx0);
        ctx1 = MFMA32(pa[0], vf01, ctx1);
        ctx1 = MFMA32(pa[1], vf11, ctx1);
    }

    float den_full = den + __shfl_xor(den, 32);

    if (kh == 1) {
        if (l < 32) lds_den[qg][l] = den_full;
#pragma unroll
        for (int r = 0; r < 16; ++r) {
            int qr = (r & 3) + 8 * (r >> 2) + 4 * h5;
            lds_ctx[qg][qr][lq] = ctx0[r];
            lds_ctx[qg][qr][32 + lq] = ctx1[r];
        }
    }
    __syncthreads();
    if (kh == 0) {
        float den_tot = den_full + lds_den[qg][lq];
#pragma unroll
        for (int r = 0; r < 16; ++r) {
            int qr = (r & 3) + 8 * (r >> 2) + 4 * h5;
            float dn = 1.0f / __shfl(den_tot, qr);
            size_t rowoff = ((size_t)b * SEQ + q0 + qr) * HID + hd * HDIM;
            out[rowoff + lq]      = (ctx0[r] + lds_ctx[qg][qr][lq]) * dn;
            out[rowoff + 32 + lq] = (ctx1[r] + lds_ctx[qg][qr][32 + lq]) * dn;
        }
    }
}

extern "C" void kernel_launch(void* const* d_in, const int* in_sizes, int n_in,
                              void* d_out, int out_size, void* d_ws, size_t ws_size,
                              hipStream_t stream) {
    const float* hs   = (const float*)d_in[0];
    const float* mask = (const float*)d_in[1];
    const float* Wq   = (const float*)d_in[2];
    const float* bq   = (const float*)d_in[3];
    const float* Wk   = (const float*)d_in[4];
    const float* bk   = (const float*)d_in[5];
    const float* Wv   = (const float*)d_in[6];
    const float* bv   = (const float*)d_in[7];
    float* out = (float*)d_out;

    char* ws = (char*)d_ws;
    unsigned short* hsb = (unsigned short*)(ws);           // 128x48 frags
    unsigned short* wb  = (unsigned short*)(ws + 6291456); // 72x48 frags
    unsigned short* Qf  = (unsigned short*)(ws + 9830400);
    unsigned short* Kf  = (unsigned short*)(ws + 16121856);
    unsigned short* VTf = (unsigned short*)(ws + 22413312);

    cvt_all_kernel<<<800, 256, 0, stream>>>((const float4*)hs, (const float4*)Wq,
                                            (const float4*)Wk, (const float4*)Wv,
                                            hsb, wb);
    qkv_gemm_kernel<<<768, 512, 0, stream>>>(hsb, wb, bq, bk, bv, Qf, Kf, VTf);
    attn_kernel<<<768, 256, 0, stream>>>(Qf, Kf, VTf, mask, out);
}

// Round 19
// 56.154 us; speedup vs baseline: 1.0018x; 1.0018x over previous
//
#include <hip/hip_runtime.h>
#include <hip/hip_bf16.h>

typedef __bf16 bf16x8 __attribute__((ext_vector_type(8)));
typedef float f32x4 __attribute__((ext_vector_type(4)));
typedef float f32x16 __attribute__((ext_vector_type(16)));
typedef unsigned int u32x2 __attribute__((ext_vector_type(2)));
typedef unsigned int u32x4 __attribute__((ext_vector_type(4)));
typedef unsigned short us8 __attribute__((ext_vector_type(8)));

#define MFMA32(a, b, c) __builtin_amdgcn_mfma_f32_32x32x16_bf16((a), (b), (c), 0, 0, 0)

// ---- constants ----
#define BATCH 8
#define SEQ 512
#define HID 768
#define NHEAD 12
#define HDIM 64

__device__ __forceinline__ unsigned short f2bf(float f) {
    unsigned int u = __float_as_uint(f);
    u += 0x7fffu + ((u >> 16) & 1u);
    return (unsigned short)(u >> 16);
}

__device__ __forceinline__ unsigned int cvtpk_bf16(float lo, float hi) {
    unsigned int r;
    asm("v_cvt_pk_bf16_f32 %0, %1, %2" : "=v"(r) : "v"(lo), "v"(hi));
    return r;
}

// ---- cvt v2 (unchanged): fp32 -> bf16 fragment-tiled, LDS-transposed ----
__global__ __launch_bounds__(256) void cvt_all_kernel(const float4* __restrict__ hs,
                                                      const float4* __restrict__ Wq,
                                                      const float4* __restrict__ Wk,
                                                      const float4* __restrict__ Wv,
                                                      unsigned short* __restrict__ hsb,
                                                      unsigned short* __restrict__ wb) {
    __shared__ us8 lds[768];   // 12 KB; index = cell ^ (row&7)

    const int tid = threadIdx.x;
    const int id = blockIdx.x;       // 0..799
    const int T = id >> 2;           // tile 0..199
    const int q = id & 3;            // kt-quarter 0..3

    const float4* src;
    int row0;
    unsigned short* dst;
    int Tout;
    if (T < 128) {
        src = hs; row0 = T * 32; dst = hsb; Tout = T;
    } else {
        int tw = T - 128;
        int which = tw / 24;
        src = (which == 0) ? Wq : ((which == 1) ? Wk : Wv);
        row0 = (tw - which * 24) * 32;
        dst = wb; Tout = tw;
    }

#pragma unroll
    for (int it = 0; it < 3; ++it) {
        int g = it * 256 + tid;
        int row = g / 24, ccl = g - row * 24;
        int fidx = (row0 + row) * 192 + (q * 24 + ccl) * 2;
        float4 v0 = src[fidx], v1 = src[fidx + 1];
        us8 o;
        o[0] = f2bf(v0.x); o[1] = f2bf(v0.y); o[2] = f2bf(v0.z); o[3] = f2bf(v0.w);
        o[4] = f2bf(v1.x); o[5] = f2bf(v1.y); o[6] = f2bf(v1.z); o[7] = f2bf(v1.w);
        int cell = row * 24 + ccl;
        lds[cell ^ (row & 7)] = o;
    }
    __syncthreads();

    const int w = tid >> 6, l = tid & 63;
    const int row = l & 31, h5 = l >> 5;
#pragma unroll
    for (int j = 0; j < 3; ++j) {
        int ktl = w * 3 + j;
        int kt = q * 12 + ktl;
        int cell = row * 24 + ktl * 2 + h5;
        us8 o = lds[cell ^ (row & 7)];
        *reinterpret_cast<us8*>(dst + ((size_t)Tout * 48 + kt) * 512 + l * 8) = o;
    }
}

// ---- fused QKV GEMM v11: 64x192 tiles, 4 waves, 64Mx96N per wave ----
// Wave (qn, kh): 2 A-streams + 3 B-streams -> 6 MFMA32/kt per 5KB loaded
// (1.6x the arithmetic intensity of v10). Split-K=2, 48KB combine LDS,
// fragment-emitting epilogue (Qf/Kf/VTf layouts unchanged).
__global__ __launch_bounds__(256) void qkv_gemm_kernel(const unsigned short* __restrict__ hsb,
                                                       const unsigned short* __restrict__ wb,
                                                       const float* __restrict__ bq,
                                                       const float* __restrict__ bk,
                                                       const float* __restrict__ bv,
                                                       unsigned short* __restrict__ Qf,
                                                       unsigned short* __restrict__ Kf,
                                                       unsigned short* __restrict__ VTf) {
    __shared__ __align__(16) char smem[49152];
    float* combine = (float*)smem;                  // [2 qn][6 accs][16 r][64 l]
    unsigned short* tb = (unsigned short*)smem;     // transpose buf (<= 24KB used)

    const int tid = threadIdx.x;
    const int w = tid >> 6;               // 0..3
    const int l = tid & 63;
    const int lq = l & 31, h5 = l >> 5;
    const int qn = w & 1;                 // N-half (96 cols)
    const int kh = w >> 1;                // K-half: 0 -> kt 0..23, 1 -> kt 24..47

    // XCD remap: 768 tiles = 64 tm x 12 tn; xcd owns 16tm x 6tn
    const int id = blockIdx.x;            // 0..767
    const int xcd = id & 7, j = id >> 3;  // j in [0,96) = 16 x 6
    const int tm = (xcd >> 1) * 16 + j / 6;   // 0..63  (64 M-rows each)
    const int tn = (xcd & 1) * 6 + j % 6;     // 0..11  (192 N-cols each)

    const int fa0 = tm * 2;               // A frag-rows fa0, fa0+1
    const int fb0 = tn * 6 + qn * 3;      // B frag-cols fb0..fb0+2

    const unsigned short* paA = hsb + (size_t)fa0 * 48 * 512 + kh * 24 * 512 + l * 8;
    const unsigned short* paB = paA + 48 * 512;
    const unsigned short* pb0 = wb + (size_t)fb0 * 48 * 512 + kh * 24 * 512 + l * 8;
    const unsigned short* pb1 = pb0 + 48 * 512;
    const unsigned short* pb2 = pb1 + 48 * 512;

    f32x16 a00 = {}, a01 = {}, a02 = {}, a10 = {}, a11 = {}, a12 = {};

#pragma unroll 2
    for (int kt = 0; kt < 24; ++kt) {
        bf16x8 a0 = *reinterpret_cast<const bf16x8*>(paA + kt * 512);
        bf16x8 a1 = *reinterpret_cast<const bf16x8*>(paB + kt * 512);
        bf16x8 b0 = *reinterpret_cast<const bf16x8*>(pb0 + kt * 512);
        bf16x8 b1 = *reinterpret_cast<const bf16x8*>(pb1 + kt * 512);
        bf16x8 b2 = *reinterpret_cast<const bf16x8*>(pb2 + kt * 512);
        a00 = MFMA32(a0, b0, a00);
        a01 = MFMA32(a0, b1, a01);
        a02 = MFMA32(a0, b2, a02);
        a10 = MFMA32(a1, b0, a10);
        a11 = MFMA32(a1, b1, a11);
        a12 = MFMA32(a1, b2, a12);
    }

    f32x16 accs[2][3] = {{a00, a01, a02}, {a10, a11, a12}};

    // ---- split-K combine: kh=1 stores value-major (lane-contiguous, conflict-free) ----
    if (kh == 1) {
#pragma unroll
        for (int mi = 0; mi < 2; ++mi)
#pragma unroll
            for (int ni = 0; ni < 3; ++ni)
#pragma unroll
                for (int r = 0; r < 16; ++r)
                    combine[((size_t)qn * 96 + (mi * 3 + ni) * 16 + r) * 64 + l] = accs[mi][ni][r];
    }
    __syncthreads();
    if (kh == 0) {
#pragma unroll
        for (int mi = 0; mi < 2; ++mi)
#pragma unroll
            for (int ni = 0; ni < 3; ++ni)
#pragma unroll
                for (int r = 0; r < 16; ++r)
                    accs[mi][ni][r] += combine[((size_t)qn * 96 + (mi * 3 + ni) * 16 + r) * 64 + l];
    }
    __syncthreads();   // combine reads done; smem reusable as transpose buffer

    const int which = tn / 4;             // 0=Q (tn 0-3), 1=K (4-7), 2=V (8-11)
    const int b = tm >> 3;                // batch (8 tm-tiles of 64 rows = 512)

    // ---- phase A (kh==0, 2 waves): bias+scale, bf16, write swizzled LDS ----
    // Q/K layout: [s_local 64][d byte 384], swizzle low 7 bits by (s&7)<<4.
    // V  layout: [d_local 192][s byte 128], swizzle by (d&7)<<4.
    if (kh == 0) {
#pragma unroll
        for (int ni = 0; ni < 3; ++ni) {
            int d_local = qn * 96 + ni * 32 + lq;        // 0..191
            int col = tn * 192 + d_local;
            int oo = col - which * HID;
            const float* bias = (which == 0) ? bq : ((which == 1) ? bk : bv);
            float bvv = bias[oo];
            float scale = (which == 0) ? 0.125f : 1.0f;
#pragma unroll
            for (int mi = 0; mi < 2; ++mi) {
#pragma unroll
                for (int g = 0; g < 4; ++g) {
                    int s_base = mi * 32 + 8 * g + 4 * h5;   // 4-aligned, 0..60
                    if (which == 2) {
                        ushort4 pk;
                        pk.x = f2bf(accs[mi][ni][4 * g + 0] + bvv);
                        pk.y = f2bf(accs[mi][ni][4 * g + 1] + bvv);
                        pk.z = f2bf(accs[mi][ni][4 * g + 2] + bvv);
                        pk.w = f2bf(accs[mi][ni][4 * g + 3] + bvv);
                        int byte = d_local * 128 + ((s_base * 2) ^ ((d_local & 7) << 4));
                        *reinterpret_cast<ushort4*>((char*)tb + byte) = pk;
                    } else {
#pragma unroll
                        for (int r2 = 0; r2 < 4; ++r2) {
                            int s_local = s_base + r2;
                            int dbyte = d_local * 2;
                            int byte = s_local * 384 + (dbyte & 0x180)
                                     + ((dbyte ^ ((s_local & 7) << 4)) & 0x7F);
                            *reinterpret_cast<unsigned short*>((char*)tb + byte) =
                                f2bf((accs[mi][ni][4 * g + r2] + bvv) * scale);
                        }
                    }
                }
            }
        }
    }
    __syncthreads();

    // ---- phase B (all 4 waves, 6 frags each = 24 frags/tile): coalesced writes ----
    if (which != 2) {
        unsigned short* dstF = (which == 0) ? Qf : Kf;
        const int tnb = tn - which * 4;
#pragma unroll
        for (int j2 = 0; j2 < 6; ++j2) {
            int fi = w * 6 + j2;                  // 0..23 = (qt_l*3 + hl)*4 + dc
            int dc = fi & 3;
            int t2 = fi >> 2;                     // 0..5
            int hl = t2 % 3, qt_l = t2 / 3;
            int head = tnb * 3 + hl;
            int qt = (tm & 7) * 2 + qt_l;
            int s_local = qt_l * 32 + lq;
            int dbyte = (hl * 64 + dc * 16 + h5 * 8) * 2;
            int byte = s_local * 384 + (dbyte & 0x180)
                     + ((dbyte ^ ((s_local & 7) << 4)) & 0x7F);
            us8 v = *reinterpret_cast<const us8*>((char*)tb + byte);
            size_t off = ((((size_t)(b * NHEAD + head)) * 16 + qt) * 4 + dc) * 512 + l * 8;
            *reinterpret_cast<us8*>(dstF + off) = v;
        }
    } else {
#pragma unroll
        for (int j2 = 0; j2 < 6; ++j2) {
            int fi = w * 6 + j2;                  // 0..23 = (nt*3 + hl)*4 + kt2l
            int kt2l = fi & 3;
            int t2 = fi >> 2;
            int hl = t2 % 3, nt = t2 / 3;
            int head = (tn - 8) * 3 + hl;
            int d_local = hl * 64 + nt * 32 + lq;
            int sbyte = kt2l * 32 + h5 * 16;
            int byte = d_local * 128 + (sbyte ^ ((d_local & 7) << 4));
            us8 v = *reinterpret_cast<const us8*>((char*)tb + byte);
            int kt2 = (tm & 7) * 4 + kt2l;
            size_t off = ((((size_t)(b * NHEAD + head)) * 2 + nt) * 32 + kt2) * 512 + l * 8;
            *reinterpret_cast<us8*>(VTf + off) = v;
        }
    }
}

// ---- attention v7 (unchanged): fully-unrolled kb loop, fragment-tiled loads ----
__global__ __launch_bounds__(256, 3) void attn_kernel(const unsigned short* __restrict__ Qf,
                                                      const unsigned short* __restrict__ Kf,
                                                      const unsigned short* __restrict__ VTf,
                                                      const float* __restrict__ mask,
                                                      float* __restrict__ out) {
    __shared__ float lds_ctx[2][32][64];   // 16 KB
    __shared__ float lds_den[2][32];       // 256 B

    const int tid = threadIdx.x;
    const int w = tid >> 6;
    const int l = tid & 63;
    const int lq = l & 31;
    const int h5 = l >> 5;
    const int qg = w & 1;
    const int kh = w >> 1;

    const int id = blockIdx.x;   // 0..767
    const int hh = id % 96;
    const int qb = id / 96;
    const int b = hh / 12;
    const int hd = hh % 12;

    const int bh = b * NHEAD + hd;
    const int q0 = qb * 64 + qg * 32;
    const float4* mask4 = (const float4*)mask;

    bf16x8 qf[4];
    {
        const unsigned short* qbase = Qf + (((size_t)bh * 16 + (qb * 2 + qg)) * 4) * 512 + l * 8;
#pragma unroll
        for (int dc = 0; dc < 4; ++dc)
            qf[dc] = *reinterpret_cast<const bf16x8*>(qbase + dc * 512);
    }

    const unsigned short* kbase  = Kf + (((size_t)bh * 16 + kh * 8) * 4) * 512 + l * 8;
    const unsigned short* vbase0 = VTf + (((size_t)bh * 2 + 0) * 32 + kh * 16) * 512 + l * 8;
    const unsigned short* vbase1 = VTf + (((size_t)bh * 2 + 1) * 32 + kh * 16) * 512 + l * 8;

    f32x16 ctx0 = {};
    f32x16 ctx1 = {};
    float den = 0.f;

#pragma unroll
    for (int kb = 0; kb < 8; ++kb) {
        bf16x8 kf[4];
#pragma unroll
        for (int dc = 0; dc < 4; ++dc)
            kf[dc] = *reinterpret_cast<const bf16x8*>(kbase + (kb * 4 + dc) * 512);

        f32x16 T = {};
#pragma unroll
        for (int dc = 0; dc < 4; ++dc)
            T = MFMA32(kf[dc], qf[dc], T);

        bf16x8 vf00 = *reinterpret_cast<const bf16x8*>(vbase0 + kb * 2 * 512);
        bf16x8 vf10 = *reinterpret_cast<const bf16x8*>(vbase0 + (kb * 2 + 1) * 512);
        bf16x8 vf01 = *reinterpret_cast<const bf16x8*>(vbase1 + kb * 2 * 512);
        bf16x8 vf11 = *reinterpret_cast<const bf16x8*>(vbase1 + (kb * 2 + 1) * 512);

        const int k0 = kh * 256 + kb * 32;
        float4 mv[4];
#pragma unroll
        for (int g = 0; g < 4; ++g)
            mv[g] = mask4[b * 128 + (k0 >> 2) + 2 * g + h5];

        float p[16];
#pragma unroll
        for (int r = 0; r < 16; ++r) {
            float mval = (r & 3) == 0 ? mv[r >> 2].x : ((r & 3) == 1 ? mv[r >> 2].y
                       : ((r & 3) == 2 ? mv[r >> 2].z : mv[r >> 2].w));
            p[r] = __expf(T[r] + mval);
            den += p[r];
        }

        bf16x8 pa[2];
#pragma unroll
        for (int c = 0; c < 2; ++c) {
            int base = c * 8;
            unsigned int lo01 = cvtpk_bf16(p[base + 0], p[base + 1]);
            unsigned int lo23 = cvtpk_bf16(p[base + 2], p[base + 3]);
            unsigned int hi01 = cvtpk_bf16(p[base + 4], p[base + 5]);
            unsigned int hi23 = cvtpk_bf16(p[base + 6], p[base + 7]);
            u32x2 s1 = __builtin_amdgcn_permlane32_swap(lo01, hi01, false, false);  // {w0, w2}
            u32x2 s2 = __builtin_amdgcn_permlane32_swap(lo23, hi23, false, false);  // {w1, w3}
            u32x4 words = {s1[0], s2[0], s1[1], s2[1]};
            pa[c] = __builtin_bit_cast(bf16x8, words);
        }

        ctx0 = MFMA32(pa[0], vf00, ctx0);
        ctx0 = MFMA32(pa[1], vf10, ctx0);
        ctx1 = MFMA32(pa[0], vf01, ctx1);
        ctx1 = MFMA32(pa[1], vf11, ctx1);
    }

    float den_full = den + __shfl_xor(den, 32);

    if (kh == 1) {
        if (l < 32) lds_den[qg][l] = den_full;
#pragma unroll
        for (int r = 0; r < 16; ++r) {
            int qr = (r & 3) + 8 * (r >> 2) + 4 * h5;
            lds_ctx[qg][qr][lq] = ctx0[r];
            lds_ctx[qg][qr][32 + lq] = ctx1[r];
        }
    }
    __syncthreads();
    if (kh == 0) {
        float den_tot = den_full + lds_den[qg][lq];
#pragma unroll
        for (int r = 0; r < 16; ++r) {
            int qr = (r & 3) + 8 * (r >> 2) + 4 * h5;
            float dn = 1.0f / __shfl(den_tot, qr);
            size_t rowoff = ((size_t)b * SEQ + q0 + qr) * HID + hd * HDIM;
            out[rowoff + lq]      = (ctx0[r] + lds_ctx[qg][qr][lq]) * dn;
            out[rowoff + 32 + lq] = (ctx1[r] + lds_ctx[qg][qr][32 + lq]) * dn;
        }
    }
}

extern "C" void kernel_launch(void* const* d_in, const int* in_sizes, int n_in,
                              void* d_out, int out_size, void* d_ws, size_t ws_size,
                              hipStream_t stream) {
    const float* hs   = (const float*)d_in[0];
    const float* mask = (const float*)d_in[1];
    const float* Wq   = (const float*)d_in[2];
    const float* bq   = (const float*)d_in[3];
    const float* Wk   = (const float*)d_in[4];
    const float* bk   = (const float*)d_in[5];
    const float* Wv   = (const float*)d_in[6];
    const float* bv   = (const float*)d_in[7];
    float* out = (float*)d_out;

    char* ws = (char*)d_ws;
    unsigned short* hsb = (unsigned short*)(ws);           // 128x48 frags
    unsigned short* wb  = (unsigned short*)(ws + 6291456); // 72x48 frags
    unsigned short* Qf  = (unsigned short*)(ws + 9830400);
    unsigned short* Kf  = (unsigned short*)(ws + 16121856);
    unsigned short* VTf = (unsigned short*)(ws + 22413312);

    cvt_all_kernel<<<800, 256, 0, stream>>>((const float4*)hs, (const float4*)Wq,
                                            (const float4*)Wk, (const float4*)Wv,
                                            hsb, wb);
    qkv_gemm_kernel<<<768, 256, 0, stream>>>(hsb, wb, bq, bk, bv, Qf, Kf, VTf);
    attn_kernel<<<768, 256, 0, stream>>>(Qf, Kf, VTf, mask, out);
}

// Round 20
// 55.745 us; speedup vs baseline: 1.0092x; 1.0073x over previous
//
#include <hip/hip_runtime.h>
#include <hip/hip_bf16.h>

typedef __bf16 bf16x8 __attribute__((ext_vector_type(8)));
typedef float f32x4 __attribute__((ext_vector_type(4)));
typedef float f32x16 __attribute__((ext_vector_type(16)));
typedef unsigned int u32x2 __attribute__((ext_vector_type(2)));
typedef unsigned int u32x4 __attribute__((ext_vector_type(4)));
typedef unsigned short us8 __attribute__((ext_vector_type(8)));

#define MFMA32(a, b, c) __builtin_amdgcn_mfma_f32_32x32x16_bf16((a), (b), (c), 0, 0, 0)

// ---- constants ----
#define BATCH 8
#define SEQ 512
#define HID 768
#define NHEAD 12
#define HDIM 64

__device__ __forceinline__ unsigned short f2bf(float f) {
    unsigned int u = __float_as_uint(f);
    u += 0x7fffu + ((u >> 16) & 1u);
    return (unsigned short)(u >> 16);
}

__device__ __forceinline__ unsigned int cvtpk_bf16(float lo, float hi) {
    unsigned int r;
    asm("v_cvt_pk_bf16_f32 %0, %1, %2" : "=v"(r) : "v"(lo), "v"(hi));
    return r;
}

// ---- cvt v2 (unchanged): fp32 -> bf16 fragment-tiled, LDS-transposed ----
__global__ __launch_bounds__(256) void cvt_all_kernel(const float4* __restrict__ hs,
                                                      const float4* __restrict__ Wq,
                                                      const float4* __restrict__ Wk,
                                                      const float4* __restrict__ Wv,
                                                      unsigned short* __restrict__ hsb,
                                                      unsigned short* __restrict__ wb) {
    __shared__ us8 lds[768];   // 12 KB; index = cell ^ (row&7)

    const int tid = threadIdx.x;
    const int id = blockIdx.x;       // 0..799
    const int T = id >> 2;           // tile 0..199
    const int q = id & 3;            // kt-quarter 0..3

    const float4* src;
    int row0;
    unsigned short* dst;
    int Tout;
    if (T < 128) {
        src = hs; row0 = T * 32; dst = hsb; Tout = T;
    } else {
        int tw = T - 128;
        int which = tw / 24;
        src = (which == 0) ? Wq : ((which == 1) ? Wk : Wv);
        row0 = (tw - which * 24) * 32;
        dst = wb; Tout = tw;
    }

#pragma unroll
    for (int it = 0; it < 3; ++it) {
        int g = it * 256 + tid;
        int row = g / 24, ccl = g - row * 24;
        int fidx = (row0 + row) * 192 + (q * 24 + ccl) * 2;
        float4 v0 = src[fidx], v1 = src[fidx + 1];
        us8 o;
        o[0] = f2bf(v0.x); o[1] = f2bf(v0.y); o[2] = f2bf(v0.z); o[3] = f2bf(v0.w);
        o[4] = f2bf(v1.x); o[5] = f2bf(v1.y); o[6] = f2bf(v1.z); o[7] = f2bf(v1.w);
        int cell = row * 24 + ccl;
        lds[cell ^ (row & 7)] = o;
    }
    __syncthreads();

    const int w = tid >> 6, l = tid & 63;
    const int row = l & 31, h5 = l >> 5;
#pragma unroll
    for (int j = 0; j < 3; ++j) {
        int ktl = w * 3 + j;
        int kt = q * 12 + ktl;
        int cell = row * 24 + ktl * 2 + h5;
        us8 o = lds[cell ^ (row & 7)];
        *reinterpret_cast<us8*>(dst + ((size_t)Tout * 48 + kt) * 512 + l * 8) = o;
    }
}

// ---- fused QKV GEMM v11 (unchanged): 64x192 tiles, 4 waves, 64Mx96N per wave ----
__global__ __launch_bounds__(256) void qkv_gemm_kernel(const unsigned short* __restrict__ hsb,
                                                       const unsigned short* __restrict__ wb,
                                                       const float* __restrict__ bq,
                                                       const float* __restrict__ bk,
                                                       const float* __restrict__ bv,
                                                       unsigned short* __restrict__ Qf,
                                                       unsigned short* __restrict__ Kf,
                                                       unsigned short* __restrict__ VTf) {
    __shared__ __align__(16) char smem[49152];
    float* combine = (float*)smem;                  // [2 qn][6 accs][16 r][64 l]
    unsigned short* tb = (unsigned short*)smem;     // transpose buf (<= 24KB used)

    const int tid = threadIdx.x;
    const int w = tid >> 6;               // 0..3
    const int l = tid & 63;
    const int lq = l & 31, h5 = l >> 5;
    const int qn = w & 1;                 // N-half (96 cols)
    const int kh = w >> 1;                // K-half: 0 -> kt 0..23, 1 -> kt 24..47

    const int id = blockIdx.x;            // 0..767
    const int xcd = id & 7, j = id >> 3;  // j in [0,96) = 16 x 6
    const int tm = (xcd >> 1) * 16 + j / 6;   // 0..63  (64 M-rows each)
    const int tn = (xcd & 1) * 6 + j % 6;     // 0..11  (192 N-cols each)

    const int fa0 = tm * 2;               // A frag-rows fa0, fa0+1
    const int fb0 = tn * 6 + qn * 3;      // B frag-cols fb0..fb0+2

    const unsigned short* paA = hsb + (size_t)fa0 * 48 * 512 + kh * 24 * 512 + l * 8;
    const unsigned short* paB = paA + 48 * 512;
    const unsigned short* pb0 = wb + (size_t)fb0 * 48 * 512 + kh * 24 * 512 + l * 8;
    const unsigned short* pb1 = pb0 + 48 * 512;
    const unsigned short* pb2 = pb1 + 48 * 512;

    f32x16 a00 = {}, a01 = {}, a02 = {}, a10 = {}, a11 = {}, a12 = {};

#pragma unroll 2
    for (int kt = 0; kt < 24; ++kt) {
        bf16x8 a0 = *reinterpret_cast<const bf16x8*>(paA + kt * 512);
        bf16x8 a1 = *reinterpret_cast<const bf16x8*>(paB + kt * 512);
        bf16x8 b0 = *reinterpret_cast<const bf16x8*>(pb0 + kt * 512);
        bf16x8 b1 = *reinterpret_cast<const bf16x8*>(pb1 + kt * 512);
        bf16x8 b2 = *reinterpret_cast<const bf16x8*>(pb2 + kt * 512);
        a00 = MFMA32(a0, b0, a00);
        a01 = MFMA32(a0, b1, a01);
        a02 = MFMA32(a0, b2, a02);
        a10 = MFMA32(a1, b0, a10);
        a11 = MFMA32(a1, b1, a11);
        a12 = MFMA32(a1, b2, a12);
    }

    f32x16 accs[2][3] = {{a00, a01, a02}, {a10, a11, a12}};

    // split-K combine (value-major, conflict-free)
    if (kh == 1) {
#pragma unroll
        for (int mi = 0; mi < 2; ++mi)
#pragma unroll
            for (int ni = 0; ni < 3; ++ni)
#pragma unroll
                for (int r = 0; r < 16; ++r)
                    combine[((size_t)qn * 96 + (mi * 3 + ni) * 16 + r) * 64 + l] = accs[mi][ni][r];
    }
    __syncthreads();
    if (kh == 0) {
#pragma unroll
        for (int mi = 0; mi < 2; ++mi)
#pragma unroll
            for (int ni = 0; ni < 3; ++ni)
#pragma unroll
                for (int r = 0; r < 16; ++r)
                    accs[mi][ni][r] += combine[((size_t)qn * 96 + (mi * 3 + ni) * 16 + r) * 64 + l];
    }
    __syncthreads();

    const int which = tn / 4;             // 0=Q (tn 0-3), 1=K (4-7), 2=V (8-11)
    const int b = tm >> 3;

    // phase A (kh==0): bias+scale, bf16, write swizzled LDS
    if (kh == 0) {
#pragma unroll
        for (int ni = 0; ni < 3; ++ni) {
            int d_local = qn * 96 + ni * 32 + lq;        // 0..191
            int col = tn * 192 + d_local;
            int oo = col - which * HID;
            const float* bias = (which == 0) ? bq : ((which == 1) ? bk : bv);
            float bvv = bias[oo];
            float scale = (which == 0) ? 0.125f : 1.0f;
#pragma unroll
            for (int mi = 0; mi < 2; ++mi) {
#pragma unroll
                for (int g = 0; g < 4; ++g) {
                    int s_base = mi * 32 + 8 * g + 4 * h5;
                    if (which == 2) {
                        ushort4 pk;
                        pk.x = f2bf(accs[mi][ni][4 * g + 0] + bvv);
                        pk.y = f2bf(accs[mi][ni][4 * g + 1] + bvv);
                        pk.z = f2bf(accs[mi][ni][4 * g + 2] + bvv);
                        pk.w = f2bf(accs[mi][ni][4 * g + 3] + bvv);
                        int byte = d_local * 128 + ((s_base * 2) ^ ((d_local & 7) << 4));
                        *reinterpret_cast<ushort4*>((char*)tb + byte) = pk;
                    } else {
#pragma unroll
                        for (int r2 = 0; r2 < 4; ++r2) {
                            int s_local = s_base + r2;
                            int dbyte = d_local * 2;
                            int byte = s_local * 384 + (dbyte & 0x180)
                                     + ((dbyte ^ ((s_local & 7) << 4)) & 0x7F);
                            *reinterpret_cast<unsigned short*>((char*)tb + byte) =
                                f2bf((accs[mi][ni][4 * g + r2] + bvv) * scale);
                        }
                    }
                }
            }
        }
    }
    __syncthreads();

    // phase B (all 4 waves, 6 frags each): coalesced writes
    if (which != 2) {
        unsigned short* dstF = (which == 0) ? Qf : Kf;
        const int tnb = tn - which * 4;
#pragma unroll
        for (int j2 = 0; j2 < 6; ++j2) {
            int fi = w * 6 + j2;                  // 0..23 = (qt_l*3 + hl)*4 + dc
            int dc = fi & 3;
            int t2 = fi >> 2;
            int hl = t2 % 3, qt_l = t2 / 3;
            int head = tnb * 3 + hl;
            int qt = (tm & 7) * 2 + qt_l;
            int s_local = qt_l * 32 + lq;
            int dbyte = (hl * 64 + dc * 16 + h5 * 8) * 2;
            int byte = s_local * 384 + (dbyte & 0x180)
                     + ((dbyte ^ ((s_local & 7) << 4)) & 0x7F);
            us8 v = *reinterpret_cast<const us8*>((char*)tb + byte);
            size_t off = ((((size_t)(b * NHEAD + head)) * 16 + qt) * 4 + dc) * 512 + l * 8;
            *reinterpret_cast<us8*>(dstF + off) = v;
        }
    } else {
#pragma unroll
        for (int j2 = 0; j2 < 6; ++j2) {
            int fi = w * 6 + j2;                  // 0..23 = (nt*3 + hl)*4 + kt2l
            int kt2l = fi & 3;
            int t2 = fi >> 2;
            int hl = t2 % 3, nt = t2 / 3;
            int head = (tn - 8) * 3 + hl;
            int d_local = hl * 64 + nt * 32 + lq;
            int sbyte = kt2l * 32 + h5 * 16;
            int byte = d_local * 128 + (sbyte ^ ((d_local & 7) << 4));
            us8 v = *reinterpret_cast<const us8*>((char*)tb + byte);
            int kt2 = (tm & 7) * 4 + kt2l;
            size_t off = ((((size_t)(b * NHEAD + head)) * 2 + nt) * 32 + kt2) * 512 + l * 8;
            *reinterpret_cast<us8*>(VTf + off) = v;
        }
    }
}

// ---- attention v8: split-K 4-way. Grid 1536 = 96 bh x 16 q-groups(32 rows).
// 4 waves/block = 4 k-quarters (128 k = 4 kb each). Exact f32 merge via LDS.
__global__ __launch_bounds__(256) void attn_kernel(const unsigned short* __restrict__ Qf,
                                                   const unsigned short* __restrict__ Kf,
                                                   const unsigned short* __restrict__ VTf,
                                                   const float* __restrict__ mask,
                                                   float* __restrict__ out) {
    __shared__ float lds_ctx[3][32][64];   // 24 KB: partials from waves 1..3
    __shared__ float lds_den[3][32];       // 384 B

    const int tid = threadIdx.x;
    const int w = tid >> 6;      // k-quarter 0..3
    const int l = tid & 63;
    const int lq = l & 31;
    const int h5 = l >> 5;

    const int id = blockIdx.x;   // 0..1535
    const int hh = id % 96;      // same XCD for all q-groups of a head (96 % 8 == 0)
    const int qg = id / 96;      // 0..15 (32 q-rows each)
    const int b = hh / 12;
    const int hd = hh % 12;

    const int bh = b * NHEAD + hd;
    const int q0 = qg * 32;
    const float4* mask4 = (const float4*)mask;

    // Q fragments (qt = qg)
    bf16x8 qf[4];
    {
        const unsigned short* qbase = Qf + (((size_t)bh * 16 + qg) * 4) * 512 + l * 8;
#pragma unroll
        for (int dc = 0; dc < 4; ++dc)
            qf[dc] = *reinterpret_cast<const bf16x8*>(qbase + dc * 512);
    }

    // this wave's k-quarter: kt = w*4 .. w*4+3
    const unsigned short* kbase  = Kf + (((size_t)bh * 16 + w * 4) * 4) * 512 + l * 8;
    const unsigned short* vbase0 = VTf + (((size_t)bh * 2 + 0) * 32 + w * 8) * 512 + l * 8;
    const unsigned short* vbase1 = VTf + (((size_t)bh * 2 + 1) * 32 + w * 8) * 512 + l * 8;

    f32x16 ctx0 = {};
    f32x16 ctx1 = {};
    float den = 0.f;

#pragma unroll
    for (int kb = 0; kb < 4; ++kb) {
        bf16x8 kf[4];
#pragma unroll
        for (int dc = 0; dc < 4; ++dc)
            kf[dc] = *reinterpret_cast<const bf16x8*>(kbase + (kb * 4 + dc) * 512);

        f32x16 T = {};
#pragma unroll
        for (int dc = 0; dc < 4; ++dc)
            T = MFMA32(kf[dc], qf[dc], T);

        bf16x8 vf00 = *reinterpret_cast<const bf16x8*>(vbase0 + kb * 2 * 512);
        bf16x8 vf10 = *reinterpret_cast<const bf16x8*>(vbase0 + (kb * 2 + 1) * 512);
        bf16x8 vf01 = *reinterpret_cast<const bf16x8*>(vbase1 + kb * 2 * 512);
        bf16x8 vf11 = *reinterpret_cast<const bf16x8*>(vbase1 + (kb * 2 + 1) * 512);

        const int k0 = w * 128 + kb * 32;
        float4 mv[4];
#pragma unroll
        for (int g = 0; g < 4; ++g)
            mv[g] = mask4[b * 128 + (k0 >> 2) + 2 * g + h5];

        float p[16];
#pragma unroll
        for (int r = 0; r < 16; ++r) {
            float mval = (r & 3) == 0 ? mv[r >> 2].x : ((r & 3) == 1 ? mv[r >> 2].y
                       : ((r & 3) == 2 ? mv[r >> 2].z : mv[r >> 2].w));
            p[r] = __expf(T[r] + mval);
            den += p[r];
        }

        bf16x8 pa[2];
#pragma unroll
        for (int c = 0; c < 2; ++c) {
            int base = c * 8;
            unsigned int lo01 = cvtpk_bf16(p[base + 0], p[base + 1]);
            unsigned int lo23 = cvtpk_bf16(p[base + 2], p[base + 3]);
            unsigned int hi01 = cvtpk_bf16(p[base + 4], p[base + 5]);
            unsigned int hi23 = cvtpk_bf16(p[base + 6], p[base + 7]);
            u32x2 s1 = __builtin_amdgcn_permlane32_swap(lo01, hi01, false, false);  // {w0, w2}
            u32x2 s2 = __builtin_amdgcn_permlane32_swap(lo23, hi23, false, false);  // {w1, w3}
            u32x4 words = {s1[0], s2[0], s1[1], s2[1]};
            pa[c] = __builtin_bit_cast(bf16x8, words);
        }

        ctx0 = MFMA32(pa[0], vf00, ctx0);
        ctx0 = MFMA32(pa[1], vf10, ctx0);
        ctx1 = MFMA32(pa[0], vf01, ctx1);
        ctx1 = MFMA32(pa[1], vf11, ctx1);
    }

    float den_full = den + __shfl_xor(den, 32);

    if (w > 0) {
        if (l < 32) lds_den[w - 1][l] = den_full;
#pragma unroll
        for (int r = 0; r < 16; ++r) {
            int qr = (r & 3) + 8 * (r >> 2) + 4 * h5;
            lds_ctx[w - 1][qr][lq] = ctx0[r];
            lds_ctx[w - 1][qr][32 + lq] = ctx1[r];
        }
    }
    __syncthreads();
    if (w == 0) {
        float den_tot = den_full + lds_den[0][lq] + lds_den[1][lq] + lds_den[2][lq];
#pragma unroll
        for (int r = 0; r < 16; ++r) {
            int qr = (r & 3) + 8 * (r >> 2) + 4 * h5;
            float dn = 1.0f / __shfl(den_tot, qr);
            size_t rowoff = ((size_t)b * SEQ + q0 + qr) * HID + hd * HDIM;
            out[rowoff + lq] = (ctx0[r] + lds_ctx[0][qr][lq] + lds_ctx[1][qr][lq]
                                + lds_ctx[2][qr][lq]) * dn;
            out[rowoff + 32 + lq] = (ctx1[r] + lds_ctx[0][qr][32 + lq] + lds_ctx[1][qr][32 + lq]
                                     + lds_ctx[2][qr][32 + lq]) * dn;
        }
    }
}

extern "C" void kernel_launch(void* const* d_in, const int* in_sizes, int n_in,
                              void* d_out, int out_size, void* d_ws, size_t ws_size,
                              hipStream_t stream) {
    const float* hs   = (const float*)d_in[0];
    const float* mask = (const float*)d_in[1];
    const float* Wq   = (const float*)d_in[2];
    const float* bq   = (const float*)d_in[3];
    const float* Wk   = (const float*)d_in[4];
    const float* bk   = (const float*)d_in[5];
    const float* Wv   = (const float*)d_in[6];
    const float* bv   = (const float*)d_in[7];
    float* out = (float*)d_out;

    char* ws = (char*)d_ws;
    unsigned short* hsb = (unsigned short*)(ws);           // 128x48 frags
    unsigned short* wb  = (unsigned short*)(ws + 6291456); // 72x48 frags
    unsigned short* Qf  = (unsigned short*)(ws + 9830400);
    unsigned short* Kf  = (unsigned short*)(ws + 16121856);
    unsigned short* VTf = (unsigned short*)(ws + 22413312);

    cvt_all_kernel<<<800, 256, 0, stream>>>((const float4*)hs, (const float4*)Wq,
                                            (const float4*)Wk, (const float4*)Wv,
                                            hsb, wb);
    qkv_gemm_kernel<<<768, 256, 0, stream>>>(hsb, wb, bq, bk, bv, Qf, Kf, VTf);
    attn_kernel<<<1536, 256, 0, stream>>>(Qf, Kf, VTf, mask, out);
}